// Round 1
// 859.551 us; speedup vs baseline: 1.5369x; 1.5369x over previous
//
#include <hip/hip_runtime.h>
#include <math.h>

#define B_ 16
#define S_ 2048
#define D_ 1024
#define SCALE 0.03125f   // 1/sqrt(1024)

typedef __bf16 bf16;
typedef __bf16 bf16x8 __attribute__((ext_vector_type(8)));
typedef float f32x4 __attribute__((ext_vector_type(4)));

#define MFMA(a, b, c) __builtin_amdgcn_mfma_f32_16x16x32_bf16((a), (b), (c), 0, 0, 0)

// Raw barrier: drain LDS only. Unlike __syncthreads() (which emits
// s_waitcnt vmcnt(0) lgkmcnt(0)), this lets early-issued global loads
// (vf / next kf) stay in flight ACROSS the barrier and overlap softmax.
// All cross-wave hazards here are LDS (sc/pbuf/alphaS/mS/lS) -> lgkmcnt(0)
// is sufficient. Empty asm fences stop the compiler moving LDS ops across.
#define BAR()                                           \
  do {                                                  \
    asm volatile("s_waitcnt lgkmcnt(0)" ::: "memory");  \
    __builtin_amdgcn_s_barrier();                       \
    asm volatile("" ::: "memory");                      \
  } while (0)

// ---------------------------------------------------------------------------
// Fused prep: K,V fp32 [B][S][D] -> fragment-major bf16 so every MFMA
// B-fragment load in attn is lane-contiguous (64 lanes x 16B = one 1KB
// coalesced burst) instead of a 16-row strided gather.
//   Kr[b][jt][w][kc][nt][lane][8]: elem = K[b][jt*64 + nt*16 + (l&15)]
//                                          [w*128 + kc*32 + (l>>4)*8 + j]
//   Vr[b][jt][w][ks][nt][lane][8]: elem = V[b][jt*64 + ks*32 + (l>>4)*8 + j]
//                                          [w*128 + nt*16 + (l&15)]
// One 64x128 source tile per block via LDS: coalesced fp32 reads in,
// coalesced bf16 writes out. grid (32 jt, 8 w, 16 b x {K,V}).
// ---------------------------------------------------------------------------
__global__ __launch_bounds__(256) void prep_kernel(const float* __restrict__ K,
                                                   const float* __restrict__ V,
                                                   bf16* __restrict__ Kr,
                                                   bf16* __restrict__ Vr) {
  __shared__ bf16 tile[64][136];  // pitch 136 elems = 272B: rows 16B-aligned
  const int jt = blockIdx.x;
  const int w = blockIdx.y;
  const int b = blockIdx.z & 15;
  const int isV = blockIdx.z >> 4;
  const int t = threadIdx.x;
  const float* src = (isV ? V : K) + ((size_t)b * S_ + jt * 64) * D_ + w * 128;
#pragma unroll
  for (int p = 0; p < 8; ++p) {
    const int f4 = p * 256 + t;      // 2048 float4 groups = 64 rows x 32
    const int row = f4 >> 5;
    const int c4 = (f4 & 31) * 4;
    float4 v = *(const float4*)(src + (size_t)row * D_ + c4);
    tile[row][c4 + 0] = (bf16)v.x;
    tile[row][c4 + 1] = (bf16)v.y;
    tile[row][c4 + 2] = (bf16)v.z;
    tile[row][c4 + 3] = (bf16)v.w;
  }
  __syncthreads();
  bf16* dst = (isV ? Vr : Kr) + (((size_t)b * 32 + jt) * 8 + w) * 8192;
  if (!isV) {
#pragma unroll
    for (int p = 0; p < 4; ++p) {
      const int g = p * 256 + t;     // g = (kc*4+nt)*64 + l
      const int l = g & 63;
      const int nt = (g >> 6) & 3;
      const int kc = g >> 8;
      bf16x8 o =
          *(const bf16x8*)&tile[nt * 16 + (l & 15)][kc * 32 + (l >> 4) * 8];
      *(bf16x8*)(dst + (size_t)g * 8) = o;
    }
  } else {
#pragma unroll
    for (int p = 0; p < 4; ++p) {
      const int g = p * 256 + t;     // g = (ks*8+nt)*64 + l
      const int l = g & 63;
      const int nt = (g >> 6) & 7;
      const int ks = g >> 9;
      const int sr = ks * 32 + (l >> 4) * 8;
      const int dc = nt * 16 + (l & 15);
      bf16x8 o;
#pragma unroll
      for (int j = 0; j < 8; ++j) o[j] = tile[sr + j][dc];
      *(bf16x8*)(dst + (size_t)g * 8) = o;
    }
  }
}

// ---------------------------------------------------------------------------
// Flash attention. 512 threads = 8 waves per (batch, 32-row Q tile).
// Wave w owns d-slice [128w, 128w+128): Q A-frags register-resident, partial
// QK^T -> LDS -> cross-wave reduce + online softmax (faithful fp32
// "*scale - 1e9" collapse) -> P bf16 -> PV, O in regs.
//
// R4: (1) K/V fragments come from the fragment-major Kr/Vr streams -- each
// load is a coalesced 1KB burst from a contiguous per-(chunk,wave) 16KB
// block (was: 16-cache-line strided gather per load). (2) BAR() drains
// lgkmcnt only, so the early-issued vf loads genuinely overlap phase 2.
// ---------------------------------------------------------------------------
__global__ __launch_bounds__(512, 2) void attn_kernel(
    const float* __restrict__ Q, const bf16* __restrict__ Kr,
    const bf16* __restrict__ Vr, const int* __restrict__ mask,
    float* __restrict__ out) {
  __shared__ float sc[8][32][68];   // per-wave partial scores (pad 68)
  __shared__ bf16 pbuf[32][72];     // P tile bf16 (pitch 72: 16B-aligned rows)
  __shared__ float madd[32];        // additive mask constant per row (0 or 1e9)
  __shared__ float mS[32], lS[32], alphaS[32];

  const int d = blockIdx.x;
  const int b = ((d & 7) << 1) | ((d >> 3) & 1);  // batch -> XCD pinning
  const int q0 = (d >> 4) * 32;
  const int t = threadIdx.x;
  const int w = t >> 6;          // wave 0..7
  const int lane = t & 63;
  const int n16 = lane & 15;
  const int q4 = lane >> 4;      // quad 0..3
  const int ds0 = w * 128;       // this wave's d-slice

  if (t < 32) {
    madd[t] = mask[b * S_ + q0 + t] ? 0.0f : 1e9f;
    mS[t] = -1e30f;              // finite "-inf": exp(-1e30 - m) == 0
    lS[t] = 0.0f;
  }

  const float* Qb = Q + (size_t)b * S_ * D_;
  // per-(b,w) fragment stream bases; chunk jt adds jt*64KB elems
  const bf16* Kw = Kr + ((size_t)b * 256 + w) * 8192 + (size_t)lane * 8;
  const bf16* Vw = Vr + ((size_t)b * 256 + w) * 8192 + (size_t)lane * 8;

  // Q A-fragments (fp32 -> bf16), register resident: qf[mt][kc]
  // lane holds Q[q0 + 16*mt + n16][ds0 + kc*32 + q4*8 + 0..7]
  bf16x8 qf[2][4];
#pragma unroll
  for (int mt = 0; mt < 2; ++mt)
#pragma unroll
    for (int kc = 0; kc < 4; ++kc) {
      const float* qp = Qb + (size_t)(q0 + 16 * mt + n16) * D_ +
                        ds0 + kc * 32 + q4 * 8;
      float4 a = *(const float4*)qp;
      float4 c = *(const float4*)(qp + 4);
      bf16x8 f;
      f[0] = (bf16)a.x; f[1] = (bf16)a.y; f[2] = (bf16)a.z; f[3] = (bf16)a.w;
      f[4] = (bf16)c.x; f[5] = (bf16)c.y; f[6] = (bf16)c.z; f[7] = (bf16)c.w;
      qf[mt][kc] = f;
    }

  // O accumulator: o[mt][nt][r] = O[16*mt + 4*q4 + r][ds0 + nt*16 + n16]
  f32x4 o[2][8];
#pragma unroll
  for (int mt = 0; mt < 2; ++mt)
#pragma unroll
    for (int nt = 0; nt < 8; ++nt) o[mt][nt] = (f32x4){0.f, 0.f, 0.f, 0.f};

  __syncthreads();

  for (int jt = 0; jt < 32; ++jt) {
    const bf16* kb = Kw + (size_t)jt * 65536;
    const bf16* vb = Vw + (size_t)jt * 65536;

    // ---- phase 1: partial scores S_w[32 x 64] over this wave's 128-d slice
    // kf[nt][kc]: K[k0+nt*16+n16][ds0+kc*32+q4*8+..] -- coalesced 1KB bursts
    bf16x8 kf[4][4];
#pragma unroll
    for (int kc = 0; kc < 4; ++kc)
#pragma unroll
      for (int nt = 0; nt < 4; ++nt)
        kf[nt][kc] = *(const bf16x8*)(kb + ((kc * 4 + nt) << 9));
    f32x4 acc[2][4];
#pragma unroll
    for (int mt = 0; mt < 2; ++mt)
#pragma unroll
      for (int nt = 0; nt < 4; ++nt) acc[mt][nt] = (f32x4){0.f, 0.f, 0.f, 0.f};
#pragma unroll
    for (int kc = 0; kc < 4; ++kc)
#pragma unroll
      for (int nt = 0; nt < 4; ++nt)
#pragma unroll
        for (int mt = 0; mt < 2; ++mt)
          acc[mt][nt] = MFMA(qf[mt][kc], kf[nt][kc], acc[mt][nt]);

    // ---- early-issue VT fragments for phase 3 (independent of softmax);
    // with BAR() they stay in flight through both barriers.
    bf16x8 vf[2][8];  // [ks][nt]: VT[ds0 + nt*16 + n16][k0 + ks*32 + q4*8+..]
#pragma unroll
    for (int ks = 0; ks < 2; ++ks)
#pragma unroll
      for (int nt = 0; nt < 8; ++nt)
        vf[ks][nt] = *(const bf16x8*)(vb + ((ks * 8 + nt) << 9));

    // write partials: row = 16*mt + 4*q4 + r, col = nt*16 + n16
#pragma unroll
    for (int mt = 0; mt < 2; ++mt)
#pragma unroll
      for (int nt = 0; nt < 4; ++nt)
#pragma unroll
        for (int r = 0; r < 4; ++r)
          sc[w][16 * mt + 4 * q4 + r][nt * 16 + n16] = acc[mt][nt][r];
    BAR();

    // ---- phase 2: cross-wave reduce + online softmax (32 rows x 16 thr)
    {
      const int r = t >> 4;
      const int cg = t & 15;
      const int c0 = cg * 4;
      float s0v = 0.f, s1v = 0.f, s2v = 0.f, s3v = 0.f;
#pragma unroll
      for (int ww = 0; ww < 8; ++ww) {
        float4 v = *(const float4*)&sc[ww][r][c0];
        s0v += v.x; s1v += v.y; s2v += v.z; s3v += v.w;
      }
      const float ma = madd[r];
      // faithful fp32 order: (dot * scale) then subtract 1e9 -> bit-collapse
      s0v = s0v * SCALE - ma;
      s1v = s1v * SCALE - ma;
      s2v = s2v * SCALE - ma;
      s3v = s3v * SCALE - ma;
      float mx = fmaxf(fmaxf(s0v, s1v), fmaxf(s2v, s3v));
      mx = fmaxf(mx, __shfl_xor(mx, 1));
      mx = fmaxf(mx, __shfl_xor(mx, 2));
      mx = fmaxf(mx, __shfl_xor(mx, 4));
      mx = fmaxf(mx, __shfl_xor(mx, 8));
      const float m_old = mS[r];
      const float m_new = fmaxf(m_old, mx);
      const float p0 = __expf(s0v - m_new);
      const float p1 = __expf(s1v - m_new);
      const float p2 = __expf(s2v - m_new);
      const float p3 = __expf(s3v - m_new);
      float ps = (p0 + p1) + (p2 + p3);
      ps += __shfl_xor(ps, 1);
      ps += __shfl_xor(ps, 2);
      ps += __shfl_xor(ps, 4);
      ps += __shfl_xor(ps, 8);
      if (cg == 0) {
        const float al = __expf(m_old - m_new);  // 0 on first chunk
        alphaS[r] = al;
        lS[r] = lS[r] * al + ps;
        mS[r] = m_new;
      }
      pbuf[r][c0 + 0] = (bf16)p0;
      pbuf[r][c0 + 1] = (bf16)p1;
      pbuf[r][c0 + 2] = (bf16)p2;
      pbuf[r][c0 + 3] = (bf16)p3;
    }
    BAR();

    // ---- phase 3: rescale O by alpha, then O += P @ V_chunk
    f32x4 av[2];
#pragma unroll
    for (int mt = 0; mt < 2; ++mt)
#pragma unroll
      for (int rg = 0; rg < 4; ++rg) av[mt][rg] = alphaS[16 * mt + 4 * q4 + rg];
#pragma unroll
    for (int mt = 0; mt < 2; ++mt)
#pragma unroll
      for (int nt = 0; nt < 8; ++nt) o[mt][nt] *= av[mt];

    bf16x8 pf[2][2];  // P A-frags: P[16*mt + n16][ks*32 + q4*8 + 0..7]
#pragma unroll
    for (int mt = 0; mt < 2; ++mt)
#pragma unroll
      for (int ks = 0; ks < 2; ++ks)
        pf[mt][ks] = *(const bf16x8*)&pbuf[16 * mt + n16][ks * 32 + q4 * 8];

#pragma unroll
    for (int ks = 0; ks < 2; ++ks)
#pragma unroll
      for (int nt = 0; nt < 8; ++nt)
#pragma unroll
        for (int mt = 0; mt < 2; ++mt)
          o[mt][nt] = MFMA(pf[mt][ks], vf[ks][nt], o[mt][nt]);
  }

  // ---- epilogue: divide by row sums, store fp32
  f32x4 invl[2];
#pragma unroll
  for (int mt = 0; mt < 2; ++mt)
#pragma unroll
    for (int rg = 0; rg < 4; ++rg)
      invl[mt][rg] = 1.0f / lS[16 * mt + 4 * q4 + rg];
#pragma unroll
  for (int mt = 0; mt < 2; ++mt)
#pragma unroll
    for (int nt = 0; nt < 8; ++nt)
#pragma unroll
      for (int rg = 0; rg < 4; ++rg) {
        const size_t row = (size_t)b * S_ + q0 + 16 * mt + 4 * q4 + rg;
        out[row * D_ + ds0 + nt * 16 + n16] = o[mt][nt][rg] * invl[mt][rg];
      }
}

// ---------------------------------------------------------------------------
extern "C" void kernel_launch(void* const* d_in, const int* in_sizes, int n_in,
                              void* d_out, int out_size, void* d_ws, size_t ws_size,
                              hipStream_t stream) {
  (void)in_sizes; (void)n_in; (void)out_size; (void)ws_size;
  const float* Q = (const float*)d_in[0];
  const float* K = (const float*)d_in[1];
  const float* V = (const float*)d_in[2];
  const int* mask = (const int*)d_in[3];
  float* out = (float*)d_out;
  bf16* Kr = (bf16*)d_ws;                              // 64 MiB
  bf16* Vr = (bf16*)d_ws + (size_t)B_ * S_ * D_;       // next 64 MiB

  prep_kernel<<<dim3(32, 8, 32), 256, 0, stream>>>(K, V, Kr, Vr);
  attn_kernel<<<B_ * (S_ / 32), 512, 0, stream>>>(Q, Kr, Vr, mask, out);
}